// Round 6
// baseline (737.872 us; speedup 1.0000x reference)
//
#include <hip/hip_runtime.h>
#include <hip/hip_bf16.h>

#define B_  512
#define S_  196
#define D_  1024
#define A_  512
#define O_  1000
#define NROW (B_ * S_)   // 100352

typedef __attribute__((ext_vector_type(8))) __bf16 bf16x8_t;
typedef __attribute__((ext_vector_type(16))) float f32x16;
typedef __attribute__((ext_vector_type(4))) float f32x4v;

__device__ __forceinline__ unsigned short f2bf(float f) {
    union { float f; unsigned u; } v; v.f = f;
    unsigned r = v.u + 0x7FFFu + ((v.u >> 16) & 1u);   // RNE
    return (unsigned short)(r >> 16);
}
__device__ __forceinline__ unsigned pk2(float lo, float hi) {
    return (unsigned)f2bf(lo) | ((unsigned)f2bf(hi) << 16);
}
__device__ __forceinline__ float bf2f(unsigned short h) {
    union { unsigned u; float f; } v; v.u = ((unsigned)h) << 16;
    return v.f;
}

// ---- img [NROW][1024] f32 -> imgbf bf16, 16B slots swizzled: slot' = slot ^ (row&7)
__global__ void img2bf(const float* __restrict__ img, unsigned short* __restrict__ imgbf) {
    size_t gid = (size_t)blockIdx.x * 256 + threadIdx.x;
    int row = (int)(gid >> 7);
    int c   = (int)(gid & 127);
    int kb = c >> 3, slot = c & 7;
    const float* src = &img[(size_t)row * D_ + kb * 64 + slot * 8];
    f32x4v v0 = __builtin_nontemporal_load(reinterpret_cast<const f32x4v*>(src));
    f32x4v v1 = __builtin_nontemporal_load(reinterpret_cast<const f32x4v*>(src + 4));
    uint4 u;
    u.x = pk2(v0.x, v0.y); u.y = pk2(v0.z, v0.w);
    u.z = pk2(v1.x, v1.y); u.w = pk2(v1.z, v1.w);
    *reinterpret_cast<uint4*>(
        &imgbf[(size_t)row * D_ + kb * 64 + (slot ^ (row & 7)) * 8]) = u;
}

// ---- pack Wi [D][A] f32 -> Bp fragment-linear bf16: [nfrag(16)][kk(64)][lane(64)][8]
__global__ void bpack(const float* __restrict__ Wi, unsigned short* __restrict__ Bp) {
    int n = blockIdx.x, ks = blockIdx.y, l = threadIdx.x;
    int a  = n * 32 + (l & 31);
    int kb = ks * 16 + (l >> 5) * 8;
    unsigned short o[8];
    #pragma unroll
    for (int e = 0; e < 8; ++e) o[e] = f2bf(Wi[(size_t)(kb + e) * A_ + a]);
    *reinterpret_cast<uint4*>(&Bp[((size_t)(n * 64 + ks) * 64 + l) * 8]) =
        *reinterpret_cast<const uint4*>(o);
}

// ---- qe = q @ W + bias ; 4 rows per block
__global__ void qproj(const float* __restrict__ q, const float* __restrict__ W,
                      const float* __restrict__ bias, float* __restrict__ qe) {
    __shared__ float qs[4][D_];
    int b0 = blockIdx.x * 4;
    int a  = blockIdx.y * 256 + threadIdx.x;
    for (int i = threadIdx.x; i < 4 * D_; i += 256)
        qs[i >> 10][i & 1023] = q[(b0 + (i >> 10)) * D_ + (i & 1023)];
    __syncthreads();
    float acc[4];
    float bb = bias[a];
    #pragma unroll
    for (int j = 0; j < 4; ++j) acc[j] = bb;
    #pragma unroll 8
    for (int d = 0; d < D_; ++d) {
        float w = W[d * A_ + a];
        #pragma unroll
        for (int j = 0; j < 4; ++j) acc[j] += qs[j][d] * w;
    }
    #pragma unroll
    for (int j = 0; j < 4; ++j) qe[(b0 + j) * A_ + a] = acc[j];
}

// ---- fused: scores[row] = Ws . tanh(qe[b] + img[row]@Wi)
// 128 rows/block, 8 waves, wave tile 128x64 (4 m-frags x 2 n-frags, unique cols).
// A: pre-swizzled bf16 global -> LDS via global_load_lds(16B, NT), double-buffered.
// B: fragment-packed, L2-resident -> VGPR, full-step register double-buffer.
#define MT 128
#define KT 64
#define NT_ (D_ / KT)   // 16

__global__ __launch_bounds__(512, 2)
void score_kernel(const unsigned short* __restrict__ imgbf,
                  const unsigned short* __restrict__ Bp,
                  const float* __restrict__ qe,
                  const float* __restrict__ Ws,
                  float* __restrict__ scores)
{
    __shared__ __align__(16) unsigned short Asm[2][MT][KT];   // 32 KB
    __shared__ float ws_s[A_];
    __shared__ float qe_s[2][A_];
    __shared__ float score_s[MT];

    const int tid  = threadIdx.x;
    const int lane = tid & 63;
    const int wave = tid >> 6;                 // 0..7 : unique 64-col slice
    const long row0 = (long)blockIdx.x * MT;
    const int  b0   = (int)(row0 / S_);
    const long b0s  = (long)b0 * S_;

    if (tid < A_) {
        ws_s[tid]    = Ws[tid];
        qe_s[0][tid] = qe[b0 * A_ + tid];
        qe_s[1][tid] = (b0 + 1 < B_) ? qe[(b0 + 1) * A_ + tid] : 0.f;
    }
    if (tid < MT) score_s[tid] = 0.f;

    f32x16 acc[4][2];
    #pragma unroll
    for (int m = 0; m < 4; ++m)
        #pragma unroll
        for (int n = 0; n < 2; ++n) acc[m][n] = (f32x16)0.f;

    // A staging: per wave 2 x global_load_lds(16B) = 16 rows; NT (don't evict Bp)
    const unsigned short* g0 =
        imgbf + (size_t)(row0 + wave * 16 + (lane >> 3)) * D_ + (lane & 7) * 8;

    auto STAGE = [&](int buf, int t) {
        #pragma unroll
        for (int j = 0; j < 2; ++j) {
            const unsigned short* g = g0 + (size_t)j * 8 * D_ + t * KT;
            __builtin_amdgcn_global_load_lds(
                (const __attribute__((address_space(1))) void*)g,
                (__attribute__((address_space(3))) void*)&Asm[buf][wave * 16 + j * 8][0],
                16, 0, 2 /* NT */);
        }
    };

    const bf16x8_t* __restrict__ Bpv = reinterpret_cast<const bf16x8_t*>(Bp);
    auto LOADB = [&](bf16x8_t (&bb)[4][2], int t) {
        #pragma unroll
        for (int ks = 0; ks < 4; ++ks)
            #pragma unroll
            for (int n = 0; n < 2; ++n)
                bb[ks][n] = Bpv[((size_t)(wave * 2 + n) * 64 + (t * 4 + ks)) * 64 + lane];
    };

    auto COMPUTE = [&](int cur, bf16x8_t (&bb)[4][2]) {
        #pragma unroll
        for (int ks = 0; ks < 4; ++ks) {
            bf16x8_t afr[4];
            #pragma unroll
            for (int m = 0; m < 4; ++m) {
                int r = m * 32 + (lane & 31);
                int slot = (ks * 2 + (lane >> 5)) ^ (r & 7);
                afr[m] = *reinterpret_cast<const bf16x8_t*>(&Asm[cur][r][slot * 8]);
            }
            #pragma unroll
            for (int m = 0; m < 4; ++m)
                #pragma unroll
                for (int n = 0; n < 2; ++n)
                    acc[m][n] = __builtin_amdgcn_mfma_f32_32x32x16_bf16(
                        afr[m], bb[ks][n], acc[m][n], 0, 0, 0);
        }
    };

    bf16x8_t bb0[4][2], bb1[4][2];
    STAGE(0, 0);
    LOADB(bb0, 0);
    asm volatile("s_waitcnt vmcnt(0)" ::: "memory");
    __syncthreads();

    #pragma unroll 1
    for (int t = 0; t < NT_; t += 2) {
        if (t + 1 < NT_) { STAGE(1, t + 1); LOADB(bb1, t + 1); }
        __builtin_amdgcn_sched_barrier(0);       // prefetch issues before compute
        COMPUTE(0, bb0);
        asm volatile("s_waitcnt vmcnt(0)" ::: "memory");
        __builtin_amdgcn_s_barrier();
        __builtin_amdgcn_sched_barrier(0);
        if (t + 1 < NT_) {
            if (t + 2 < NT_) { STAGE(0, t + 2); LOADB(bb0, t + 2); }
            __builtin_amdgcn_sched_barrier(0);
            COMPUTE(1, bb1);
            asm volatile("s_waitcnt vmcnt(0)" ::: "memory");
            __builtin_amdgcn_s_barrier();
            __builtin_amdgcn_sched_barrier(0);
        }
    }

    // epilogue: Ws-weighted tanh reduction over this wave's 64 cols
    #pragma unroll
    for (int m = 0; m < 4; ++m) {
        #pragma unroll
        for (int rg = 0; rg < 16; ++rg) {
            int rl = m * 32 + (rg & 3) + ((rg >> 2) << 3) + ((lane >> 5) << 2);
            float qv;
            {
                long rowg = row0 + rl;
                qv = ((rowg - b0s) >= S_) ? qe_s[1][0] : 0.f; // placeholder, fixed below
            }
            float v = 0.f;
            #pragma unroll
            for (int n = 0; n < 2; ++n) {
                int col = wave * 64 + n * 32 + (lane & 31);
                float w  = ws_s[col];
                float q0 = qe_s[0][col], q1 = qe_s[1][col];
                float qsel = ((row0 + rl - b0s) >= S_) ? q1 : q0;
                float x = acc[m][n][rg] + qsel;
                float e = __expf(2.f * x);
                v += w * (1.f - 2.f / (e + 1.f));   // w * tanh(x)
            }
            (void)qv;
            v += __shfl_xor(v, 1);
            v += __shfl_xor(v, 2);
            v += __shfl_xor(v, 4);
            v += __shfl_xor(v, 8);
            v += __shfl_xor(v, 16);
            if ((lane & 31) == 0) atomicAdd(&score_s[rl], v);
        }
    }
    __syncthreads();
    if (tid < MT) scores[row0 + tid] = score_s[tid];
}

// ---- fused softmax(196) + weighted pool (bf16 img) + residual
__global__ __launch_bounds__(256)
void softpool(const float* __restrict__ sc, const unsigned short* __restrict__ imgbf,
              const float* __restrict__ qin, float* __restrict__ uout) {
    __shared__ float ps[S_];
    __shared__ float red1[4], red2[4];
    int b = blockIdx.x, t = threadIdx.x;
    int lane = t & 63, w = t >> 6;
    float v = (t < S_) ? sc[b * S_ + t] : -1e30f;
    float m = v;
    #pragma unroll
    for (int o = 1; o < 64; o <<= 1) m = fmaxf(m, __shfl_xor(m, o));
    if (lane == 0) red1[w] = m;
    __syncthreads();
    m = fmaxf(fmaxf(red1[0], red1[1]), fmaxf(red1[2], red1[3]));
    float e = (t < S_) ? __expf(v - m) : 0.f;
    float s = e;
    #pragma unroll
    for (int o = 1; o < 64; o <<= 1) s += __shfl_xor(s, o);
    if (lane == 0) red2[w] = s;
    __syncthreads();
    s = (red2[0] + red2[1]) + (red2[2] + red2[3]);
    if (t < S_) ps[t] = e / s;
    __syncthreads();

    // pool: thread covers logical d = c*8 + h*4 + 0..3 ; unswizzle via XOR
    int c = t >> 1, h = t & 1;
    int kb = c >> 3, slot = c & 7;
    const unsigned short* base = imgbf + (size_t)b * S_ * D_ + kb * 64 + h * 4;
    float a0 = 0.f, a1 = 0.f, a2 = 0.f, a3 = 0.f;
    int rr = (b * S_) & 7;
    #pragma unroll 4
    for (int sI = 0; sI < S_; ++sI) {
        const unsigned short* p16 = base + (size_t)sI * D_ + ((slot ^ rr) * 8);
        ushort4 uv = *reinterpret_cast<const ushort4*>(p16);
        float p = ps[sI];
        a0 += p * bf2f(uv.x); a1 += p * bf2f(uv.y);
        a2 += p * bf2f(uv.z); a3 += p * bf2f(uv.w);
        rr = (rr + 1) & 7;
    }
    int d = c * 8 + h * 4;
    float4 q4 = *reinterpret_cast<const float4*>(&qin[(size_t)b * D_ + d]);
    float4 o4 = make_float4(q4.x + a0, q4.y + a1, q4.z + a2, q4.w + a3);
    *reinterpret_cast<float4*>(&uout[(size_t)b * D_ + d]) = o4;
}

// ---- out = u @ Wfc + bfc ; 8 rows per block
__global__ void fcout(const float* __restrict__ u, const float* __restrict__ W,
                      const float* __restrict__ bias, float* __restrict__ out) {
    __shared__ float us[8][D_];
    int b0 = blockIdx.x * 8;
    int o  = blockIdx.y * 256 + threadIdx.x;
    for (int i = threadIdx.x; i < 8 * D_; i += 256)
        us[i >> 10][i & 1023] = u[(b0 + (i >> 10)) * D_ + (i & 1023)];
    __syncthreads();
    if (o < O_) {
        float acc[8];
        float bb = bias[o];
        #pragma unroll
        for (int j = 0; j < 8; ++j) acc[j] = bb;
        #pragma unroll 4
        for (int d = 0; d < D_; ++d) {
            float w = W[d * O_ + o];
            #pragma unroll
            for (int j = 0; j < 8; ++j) acc[j] += us[j][d] * w;
        }
        #pragma unroll
        for (int j = 0; j < 8; ++j) out[(b0 + j) * O_ + o] = acc[j];
    }
}

extern "C" void kernel_launch(void* const* d_in, const int* in_sizes, int n_in,
                              void* d_out, int out_size, void* d_ws, size_t ws_size,
                              hipStream_t stream) {
    (void)in_sizes; (void)n_in; (void)out_size; (void)ws_size;
    const float* ques = (const float*)d_in[0];
    const float* img  = (const float*)d_in[1];
    const float* W11  = (const float*)d_in[2];
    const float* b11  = (const float*)d_in[3];
    const float* W12  = (const float*)d_in[4];
    const float* W13  = (const float*)d_in[5];
    // d_in[6] = b13: softmax-invariant, unused
    const float* W21  = (const float*)d_in[7];
    const float* b21  = (const float*)d_in[8];
    const float* W22  = (const float*)d_in[9];
    const float* W23  = (const float*)d_in[10];
    // d_in[11] = b23: softmax-invariant, unused
    const float* Wfc  = (const float*)d_in[12];
    const float* bfc  = (const float*)d_in[13];
    float* out = (float*)d_out;

    char* ws = (char*)d_ws;
    unsigned short* imgbf = (unsigned short*)ws; ws += (size_t)NROW * D_ * 2;  // 205.5 MB
    unsigned short* Bp1 = (unsigned short*)ws; ws += (size_t)A_ * D_ * 2;      // 1 MB
    unsigned short* Bp2 = (unsigned short*)ws; ws += (size_t)A_ * D_ * 2;      // 1 MB
    float* qe = (float*)ws; ws += (size_t)B_ * A_ * 4;                         // 1 MB
    float* sc = (float*)ws; ws += (size_t)B_ * S_ * 4;                         // 392 KB
    float* u1 = (float*)ws; ws += (size_t)B_ * D_ * 4;                         // 2 MB
    float* u2 = (float*)ws;                                                    // 2 MB

    const int nscore = NROW / MT;   // 784

    img2bf<<<dim3(NROW * 128 / 256), 256, 0, stream>>>(img, imgbf);

    // hop 1
    bpack<<<dim3(16, 64), 64, 0, stream>>>(W12, Bp1);
    qproj<<<dim3(B_ / 4, A_ / 256), 256, 0, stream>>>(ques, W11, b11, qe);
    score_kernel<<<dim3(nscore), 512, 0, stream>>>(imgbf, Bp1, qe, W13, sc);
    softpool<<<dim3(B_), 256, 0, stream>>>(sc, imgbf, ques, u1);

    // hop 2
    bpack<<<dim3(16, 64), 64, 0, stream>>>(W22, Bp2);
    qproj<<<dim3(B_ / 4, A_ / 256), 256, 0, stream>>>(u1, W21, b21, qe);
    score_kernel<<<dim3(nscore), 512, 0, stream>>>(imgbf, Bp2, qe, W23, sc);
    softpool<<<dim3(B_), 256, 0, stream>>>(sc, imgbf, u1, u2);

    // final FC
    fcout<<<dim3(B_ / 8, (O_ + 255) / 256), 256, 0, stream>>>(u2, Wfc, bfc, out);
}

// Round 8
// 666.083 us; speedup vs baseline: 1.1078x; 1.1078x over previous
//
#include <hip/hip_runtime.h>
#include <hip/hip_bf16.h>

#define B_  512
#define S_  196
#define D_  1024
#define A_  512
#define O_  1000
#define NROW (B_ * S_)   // 100352 = 784 * 128

typedef __attribute__((ext_vector_type(8))) __bf16 bf16x8_t;
typedef __attribute__((ext_vector_type(4))) float f32x4;
typedef __attribute__((ext_vector_type(4))) float f32x4v;

__device__ __forceinline__ unsigned short f2bf(float f) {
    union { float f; unsigned u; } v; v.f = f;
    unsigned r = v.u + 0x7FFFu + ((v.u >> 16) & 1u);   // RNE
    return (unsigned short)(r >> 16);
}
__device__ __forceinline__ unsigned pk2(float lo, float hi) {
    return (unsigned)f2bf(lo) | ((unsigned)f2bf(hi) << 16);
}
__device__ __forceinline__ float bf2f(unsigned short h) {
    union { unsigned u; float f; } v; v.u = ((unsigned)h) << 16;
    return v.f;
}

// ---- img [NROW][1024] f32 -> imgbfP fragment-packed bf16:
//      [rfrag = row/16][ks = k/32][lane][8]  where lane = (row&15) + 16*((k&31)/8)
__global__ void img2bf(const float* __restrict__ img, unsigned short* __restrict__ imgbfP) {
    size_t gid = (size_t)blockIdx.x * 256 + threadIdx.x;
    int    lane  = (int)(gid & 63);
    size_t chunk = gid >> 6;             // (rfrag*32 + ks)
    int    ks    = (int)(chunk & 31);
    size_t rfrag = chunk >> 5;
    int row = (int)(rfrag * 16 + (lane & 15));
    int k0  = ks * 32 + (lane >> 4) * 8;
    const float* src = img + (size_t)row * D_ + k0;
    f32x4v v0 = __builtin_nontemporal_load(reinterpret_cast<const f32x4v*>(src));
    f32x4v v1 = __builtin_nontemporal_load(reinterpret_cast<const f32x4v*>(src + 4));
    uint4 u;
    u.x = pk2(v0.x, v0.y); u.y = pk2(v0.z, v0.w);
    u.z = pk2(v1.x, v1.y); u.w = pk2(v1.z, v1.w);
    *reinterpret_cast<uint4*>(&imgbfP[gid * 8]) = u;
}

// ---- Wi [D][A] f32 -> Bp fragment-packed bf16: [nf = col/16][ks][lane][8]
__global__ void bpack(const float* __restrict__ Wi, unsigned short* __restrict__ Bp) {
    int nf = blockIdx.x, ks = blockIdx.y, l = threadIdx.x;
    int col = nf * 16 + (l & 15);
    int k0  = ks * 32 + (l >> 4) * 8;
    unsigned short o[8];
    #pragma unroll
    for (int e = 0; e < 8; ++e) o[e] = f2bf(Wi[(size_t)(k0 + e) * A_ + col]);
    *reinterpret_cast<uint4*>(&Bp[(((size_t)nf * 32 + ks) * 64 + l) * 8]) =
        *reinterpret_cast<const uint4*>(o);
}

// ---- qe = q @ W + bias ; 4 rows per block
__global__ void qproj(const float* __restrict__ q, const float* __restrict__ W,
                      const float* __restrict__ bias, float* __restrict__ qe) {
    __shared__ float qs[4][D_];
    int b0 = blockIdx.x * 4;
    int a  = blockIdx.y * 256 + threadIdx.x;
    for (int i = threadIdx.x; i < 4 * D_; i += 256)
        qs[i >> 10][i & 1023] = q[(b0 + (i >> 10)) * D_ + (i & 1023)];
    __syncthreads();
    float acc[4];
    float bb = bias[a];
    #pragma unroll
    for (int j = 0; j < 4; ++j) acc[j] = bb;
    #pragma unroll 8
    for (int d = 0; d < D_; ++d) {
        float w = W[d * A_ + a];
        #pragma unroll
        for (int j = 0; j < 4; ++j) acc[j] += qs[j][d] * w;
    }
    #pragma unroll
    for (int j = 0; j < 4; ++j) qe[(b0 + j) * A_ + a] = acc[j];
}

// ---- fused score partials: scp[nb][row] = sum over cols nb*128..+127 of
//      Ws[col]*tanh(qe[b][col] + (img[row]@Wi)[col])
// m97 structure: 128x128 tile, 4 waves (2x2), 16x16x32 MFMA, wave tile 64x64,
// A+B fragment-packed -> global_load_lds(16B) -> fragment-linear LDS, 2 barriers/step.
#define MT 128

__global__ __launch_bounds__(256, 3)
void score_kernel(const unsigned short* __restrict__ imgbfP,
                  const unsigned short* __restrict__ Bp,
                  const float* __restrict__ qe,
                  const float* __restrict__ Ws,
                  float* __restrict__ scp)
{
    // [rf or nf][kk][lane][8]
    __shared__ __align__(16) unsigned short Asm[8 * 2 * 64 * 8];   // 16 KB
    __shared__ __align__(16) unsigned short Bsm[8 * 2 * 64 * 8];   // 16 KB
    __shared__ float ws_s[MT];       // this block's 128-col slice
    __shared__ float qe_s[2][MT];
    __shared__ float score_s[MT];

    const int tid  = threadIdx.x;
    const int lane = tid & 63;
    const int wave = tid >> 6;          // 0..3
    const int wm   = wave >> 1;         // row half
    const int wn   = wave & 1;          // col half

    // XCD swizzle: 3136 blocks = 8 XCD x 392; 4 col-blocks of a row panel adjacent
    const int orig = blockIdx.x;
    const int xcd  = orig & 7;
    const int j    = orig >> 3;
    const int rowpanel = xcd * 98 + (j >> 2);
    const int nb       = j & 3;

    const long row0   = (long)rowpanel * MT;
    const long rfrag0 = row0 >> 4;       // 8 rfrags per panel
    const int  b0     = (int)(row0 / S_);
    const long b0s    = (long)b0 * S_;

    if (tid < MT) {
        ws_s[tid]    = Ws[nb * MT + tid];
        qe_s[0][tid] = qe[b0 * A_ + nb * MT + tid];
        qe_s[1][tid] = (b0 + 1 < B_) ? qe[(b0 + 1) * A_ + nb * MT + tid] : 0.f;
        score_s[tid] = 0.f;
    }

    f32x4 acc[4][4];
    #pragma unroll
    for (int m = 0; m < 4; ++m)
        #pragma unroll
        for (int n = 0; n < 4; ++n) acc[m][n] = (f32x4)0.f;

    // each wave stages 4 A-chunks + 4 B-chunks of 1 KB per K-step
    auto STAGE = [&](int t) {
        #pragma unroll
        for (int c = 0; c < 4; ++c) {
            int q  = wave * 4 + c;       // 0..15
            int rf = q >> 1, kk = q & 1;
            const unsigned short* ga =
                imgbfP + (((size_t)(rfrag0 + rf) * 32 + (t * 2 + kk)) * 64 + lane) * 8;
            __builtin_amdgcn_global_load_lds(
                (const __attribute__((address_space(1))) void*)ga,
                (__attribute__((address_space(3))) void*)&Asm[((rf * 2 + kk) * 64) * 8],
                16, 0, 0);
            const unsigned short* gb =
                Bp + (((size_t)(nb * 8 + rf) * 32 + (t * 2 + kk)) * 64 + lane) * 8;
            __builtin_amdgcn_global_load_lds(
                (const __attribute__((address_space(1))) void*)gb,
                (__attribute__((address_space(3))) void*)&Bsm[((rf * 2 + kk) * 64) * 8],
                16, 0, 0);
        }
    };

    for (int t = 0; t < 16; ++t) {
        STAGE(t);
        __syncthreads();   // drains gload_lds (vmcnt0) before reads
        #pragma unroll
        for (int kk = 0; kk < 2; ++kk) {
            bf16x8_t afr[4], bfr[4];
            #pragma unroll
            for (int m = 0; m < 4; ++m)
                afr[m] = *reinterpret_cast<const bf16x8_t*>(
                    &Asm[(((wm * 4 + m) * 2 + kk) * 64 + lane) * 8]);
            #pragma unroll
            for (int n = 0; n < 4; ++n)
                bfr[n] = *reinterpret_cast<const bf16x8_t*>(
                    &Bsm[(((wn * 4 + n) * 2 + kk) * 64 + lane) * 8]);
            #pragma unroll
            for (int m = 0; m < 4; ++m)
                #pragma unroll
                for (int n = 0; n < 4; ++n)
                    acc[m][n] = __builtin_amdgcn_mfma_f32_16x16x32_bf16(
                        afr[m], bfr[n], acc[m][n], 0, 0, 0);
        }
        __syncthreads();   // LDS reads done before next stage overwrites
    }

    // epilogue: sum over this wave's 64 (block-local) cols of Ws*tanh(acc + qe)
    #pragma unroll
    for (int m = 0; m < 4; ++m) {
        #pragma unroll
        for (int r = 0; r < 4; ++r) {
            int rowl = wm * 64 + m * 16 + ((lane >> 4) << 2) + r;
            int sel  = ((row0 + rowl - b0s) >= S_) ? 1 : 0;
            float v = 0.f;
            #pragma unroll
            for (int n = 0; n < 4; ++n) {
                int coll = wn * 64 + n * 16 + (lane & 15);   // block-local 0..127
                float x = acc[m][n][r] + qe_s[sel][coll];
                float e = __expf(2.f * x);
                v += ws_s[coll] * (1.f - 2.f / (e + 1.f));   // Ws * tanh(x)
            }
            v += __shfl_xor(v, 1);
            v += __shfl_xor(v, 2);
            v += __shfl_xor(v, 4);
            v += __shfl_xor(v, 8);
            if ((lane & 15) == 0) atomicAdd(&score_s[rowl], v);
        }
    }
    __syncthreads();
    if (tid < MT) scp[(size_t)nb * NROW + row0 + tid] = score_s[tid];
}

// ---- fused: sum 4 partials -> softmax(196) -> pool over packed bf16 img -> +residual
__global__ __launch_bounds__(256)
void softpool(const float* __restrict__ scp, const unsigned short* __restrict__ imgbfP,
              const float* __restrict__ qin, float* __restrict__ uout) {
    __shared__ float ps[S_];
    __shared__ float pp[208];
    __shared__ float red1[4], red2[4];
    int b = blockIdx.x, t = threadIdx.x;
    int lane = t & 63, w = t >> 6;

    float v = -1e30f;
    if (t < S_) {
        size_t r = (size_t)b * S_ + t;
        v = scp[r] + scp[(size_t)NROW + r] + scp[2 * (size_t)NROW + r] + scp[3 * (size_t)NROW + r];
    }
    float m = v;
    #pragma unroll
    for (int o = 1; o < 64; o <<= 1) m = fmaxf(m, __shfl_xor(m, o));
    if (lane == 0) red1[w] = m;
    __syncthreads();
    m = fmaxf(fmaxf(red1[0], red1[1]), fmaxf(red1[2], red1[3]));
    float e = (t < S_) ? __expf(v - m) : 0.f;
    float s = e;
    #pragma unroll
    for (int o = 1; o < 64; o <<= 1) s += __shfl_xor(s, o);
    if (lane == 0) red2[w] = s;
    __syncthreads();
    s = (red2[0] + red2[1]) + (red2[2] + red2[3]);
    if (t < S_) ps[t] = e / s;
    __syncthreads();

    const long rfrag0 = ((long)b * S_) >> 4;
    const int  off    = (int)(((long)b * S_) & 15);   // 0,4,8,12 ; off+196 <= 208
    if (t < 208) pp[t] = (t >= off && t < off + S_) ? ps[t - off] : 0.f;
    __syncthreads();

    // wave w handles ks = w, w+4, ..., w+28 (13 rfrags each, exact cover)
    const int g  = lane >> 4;     // d-octet within ks
    const int rl = lane & 15;     // row within rfrag
    #pragma unroll 1
    for (int ki = 0; ki < 8; ++ki) {
        int ks = w + ki * 4;
        float a[8] = {0.f, 0.f, 0.f, 0.f, 0.f, 0.f, 0.f, 0.f};
        #pragma unroll 1
        for (int rf = 0; rf < 13; ++rf) {
            const unsigned short* p16 =
                imgbfP + (((size_t)(rfrag0 + rf) * 32 + ks) * 64 + lane) * 8;
            uint4 u = *reinterpret_cast<const uint4*>(p16);
            float p = pp[rf * 16 + rl];
            const unsigned short* hs = reinterpret_cast<const unsigned short*>(&u);
            #pragma unroll
            for (int e2 = 0; e2 < 8; ++e2) a[e2] += p * bf2f(hs[e2]);
        }
        #pragma unroll
        for (int e2 = 0; e2 < 8; ++e2) {
            a[e2] += __shfl_xor(a[e2], 1);
            a[e2] += __shfl_xor(a[e2], 2);
            a[e2] += __shfl_xor(a[e2], 4);
            a[e2] += __shfl_xor(a[e2], 8);
        }
        if (rl == 0) {
            int d = ks * 32 + g * 8;
            const float* qb = &qin[(size_t)b * D_ + d];
            float* ob = &uout[(size_t)b * D_ + d];
            float4 q0 = *reinterpret_cast<const float4*>(qb);
            float4 q1 = *reinterpret_cast<const float4*>(qb + 4);
            float4 o0 = make_float4(q0.x + a[0], q0.y + a[1], q0.z + a[2], q0.w + a[3]);
            float4 o1 = make_float4(q1.x + a[4], q1.y + a[5], q1.z + a[6], q1.w + a[7]);
            *reinterpret_cast<float4*>(ob)     = o0;
            *reinterpret_cast<float4*>(ob + 4) = o1;
        }
    }
}

// ---- out = u @ Wfc + bfc ; 8 rows per block
__global__ void fcout(const float* __restrict__ u, const float* __restrict__ W,
                      const float* __restrict__ bias, float* __restrict__ out) {
    __shared__ float us[8][D_];
    int b0 = blockIdx.x * 8;
    int o  = blockIdx.y * 256 + threadIdx.x;
    for (int i = threadIdx.x; i < 8 * D_; i += 256)
        us[i >> 10][i & 1023] = u[(b0 + (i >> 10)) * D_ + (i & 1023)];
    __syncthreads();
    if (o < O_) {
        float acc[8];
        float bb = bias[o];
        #pragma unroll
        for (int j = 0; j < 8; ++j) acc[j] = bb;
        #pragma unroll 4
        for (int d = 0; d < D_; ++d) {
            float w = W[d * O_ + o];
            #pragma unroll
            for (int j = 0; j < 8; ++j) acc[j] += us[j][d] * w;
        }
        #pragma unroll
        for (int j = 0; j < 8; ++j) out[(b0 + j) * O_ + o] = acc[j];
    }
}

extern "C" void kernel_launch(void* const* d_in, const int* in_sizes, int n_in,
                              void* d_out, int out_size, void* d_ws, size_t ws_size,
                              hipStream_t stream) {
    (void)in_sizes; (void)n_in; (void)out_size; (void)ws_size;
    const float* ques = (const float*)d_in[0];
    const float* img  = (const float*)d_in[1];
    const float* W11  = (const float*)d_in[2];
    const float* b11  = (const float*)d_in[3];
    const float* W12  = (const float*)d_in[4];
    const float* W13  = (const float*)d_in[5];
    // d_in[6] = b13: softmax-invariant, unused
    const float* W21  = (const float*)d_in[7];
    const float* b21  = (const float*)d_in[8];
    const float* W22  = (const float*)d_in[9];
    const float* W23  = (const float*)d_in[10];
    // d_in[11] = b23: softmax-invariant, unused
    const float* Wfc  = (const float*)d_in[12];
    const float* bfc  = (const float*)d_in[13];
    float* out = (float*)d_out;

    char* ws = (char*)d_ws;
    unsigned short* imgbfP = (unsigned short*)ws; ws += (size_t)NROW * D_ * 2;  // 205.5 MB
    unsigned short* Bp1 = (unsigned short*)ws; ws += (size_t)A_ * D_ * 2;       // 1 MB
    unsigned short* Bp2 = (unsigned short*)ws; ws += (size_t)A_ * D_ * 2;       // 1 MB
    float* qe  = (float*)ws; ws += (size_t)B_ * A_ * 4;                         // 1 MB
    float* scp = (float*)ws; ws += (size_t)4 * NROW * 4;                        // 1.6 MB
    float* u1  = (float*)ws; ws += (size_t)B_ * D_ * 4;                         // 2 MB
    float* u2  = (float*)ws;                                                    // 2 MB

    const int nscore = (NROW / MT) * 4;   // 3136

    img2bf<<<dim3(NROW / 16 * 32 * 64 / 256), 256, 0, stream>>>(img, imgbfP);

    // hop 1
    bpack<<<dim3(32, 32), 64, 0, stream>>>(W12, Bp1);
    qproj<<<dim3(B_ / 4, A_ / 256), 256, 0, stream>>>(ques, W11, b11, qe);
    score_kernel<<<dim3(nscore), 256, 0, stream>>>(imgbfP, Bp1, qe, W13, scp);
    softpool<<<dim3(B_), 256, 0, stream>>>(scp, imgbfP, ques, u1);

    // hop 2
    bpack<<<dim3(32, 32), 64, 0, stream>>>(W22, Bp2);
    qproj<<<dim3(B_ / 4, A_ / 256), 256, 0, stream>>>(u1, W21, b21, qe);
    score_kernel<<<dim3(nscore), 256, 0, stream>>>(imgbfP, Bp2, qe, W23, scp);
    softpool<<<dim3(B_), 256, 0, stream>>>(scp, imgbfP, u1, u2);

    // final FC
    fcout<<<dim3(B_ / 8, (O_ + 255) / 256), 256, 0, stream>>>(u2, Wfc, bfc, out);
}